// Round 2
// baseline (236.687 us; speedup 1.0000x reference)
//
#include <hip/hip_runtime.h>
#include <stdint.h>

// BinaryLinearWscales: out[m,n] = wscale[n] * (x @ sign(W)^T)[m,n] + wbias[n] * rowsum(x)[m]
// M = B*S = 4096, N = DOUT = 4096, K = DIN = 4096.
// Round 7: 256x256 8-phase i8 GEMM, two changes vs round 6:
//   (1) swizzle reverted to the round-5 HW-proven involution sw = (row>>1)&3
//       (round-6's (row^(row>>2))&3 measured 6.29M bank-conflict cycles; round-5's
//        measured 0 under identical read geometry).
//   (2) MFMA shape 16x16x64 -> 32x32x32 i8: +12% rate ceiling (4404 vs 3944 TOPS),
//       half the MFMA instructions, identical LDS traffic. Uniform phase:
//       6 ds_read_b128 + 8 MFMA.
//   Schedule unchanged: 4 phases/tile, stage {A,B}k1(t+1) then {A,B}k0(t+2),
//   counted vmcnt(4) at tile boundaries only, CK0 at the tail.

#define MDIM 4096
#define NDIM 4096
#define KDIM 4096

typedef int int4v  __attribute__((ext_vector_type(4)));
typedef int int16v __attribute__((ext_vector_type(16)));

__device__ __forceinline__ int pack4_rn(float a, float b, float c, float d, float inv) {
  int ia = __float2int_rn(a * inv) & 0xff;
  int ib = __float2int_rn(b * inv) & 0xff;
  int ic = __float2int_rn(c * inv) & 0xff;
  int id = __float2int_rn(d * inv) & 0xff;
  return ia | (ib << 8) | (ic << 16) | (id << 24);
}

__device__ __forceinline__ int sgn8(float v) {
  return (v > 0.f) ? 1 : ((v < 0.f) ? 0xff : 0);
}

// ---------------- fused prep (UNCHANGED: isolates gemm delta) ----------------
__global__ __launch_bounds__(256) void prep_kernel(
    const float* __restrict__ x, const float* __restrict__ w,
    char* __restrict__ xq, char* __restrict__ wsg,
    float* __restrict__ xscale, float* __restrict__ sumx) {
  const int b = blockIdx.x;
  const int tid = threadIdx.x;
  if (b < MDIM) {
    const int row = b;
    const float4* xr = (const float4*)(x + (size_t)row * KDIM);
    float4 v[4];
    float s = 0.f, amax = 0.f;
#pragma unroll
    for (int u = 0; u < 4; ++u) {
      v[u] = xr[u * 256 + tid];
      s += v[u].x + v[u].y + v[u].z + v[u].w;
      amax = fmaxf(amax, fmaxf(fmaxf(fabsf(v[u].x), fabsf(v[u].y)),
                               fmaxf(fabsf(v[u].z), fabsf(v[u].w))));
    }
#pragma unroll
    for (int off = 32; off > 0; off >>= 1) {
      s += __shfl_down(s, off, 64);
      amax = fmaxf(amax, __shfl_down(amax, off, 64));
    }
    __shared__ float rs[4], rm[4], bcast;
    if ((tid & 63) == 0) { rs[tid >> 6] = s; rm[tid >> 6] = amax; }
    __syncthreads();
    if (tid == 0) {
      sumx[row] = rs[0] + rs[1] + rs[2] + rs[3];
      float mt = fmaxf(fmaxf(rm[0], rm[1]), fmaxf(rm[2], rm[3]));
      xscale[row] = mt * (1.f / 127.f);
      bcast = (mt > 0.f) ? 127.f / mt : 0.f;
    }
    __syncthreads();
    const float inv = bcast;
    int* xo = (int*)(xq + (size_t)row * KDIM);
#pragma unroll
    for (int u = 0; u < 4; ++u)
      xo[u * 256 + tid] = pack4_rn(v[u].x, v[u].y, v[u].z, v[u].w, inv);
  } else {
    const size_t base = (size_t)(b - MDIM) * (256 * 4);
    const float4* wr = (const float4*)w;
    int* wo = (int*)wsg;
#pragma unroll
    for (int u = 0; u < 4; ++u) {
      size_t i = base + u * 256 + tid;
      float4 v = wr[i];
      wo[i] = sgn8(v.x) | (sgn8(v.y) << 8) | (sgn8(v.z) << 16) | (sgn8(v.w) << 24);
    }
  }
}

// ---------------- 256x256 8-phase i8 GEMM (32x32x32 MFMA) ----------------
__global__ __launch_bounds__(512, 2) void gemm_bin_i8_8phase(
    const char* __restrict__ A, const char* __restrict__ Bs,
    const float* __restrict__ wscale, const float* __restrict__ wbias,
    const float* __restrict__ xscale, const float* __restrict__ sumx,
    float* __restrict__ C) {
  // A region: [0,64K) = (buf*2+kh)*16384 ; B region: [64K,128K)
  __shared__ __align__(16) char sm[131072];

  const int bm = blockIdx.x >> 4, bn = blockIdx.x & 15;
  const int tm0 = bm * 256, tn0 = bn * 256;
  const int tid = threadIdx.x;
  const int lane = tid & 63, wave = tid >> 6;
  const int col32 = lane & 31, hl = lane >> 5;   // 32x32 operand: row/col = lane&31, k-chunk16 = lane>>5
  const int wr = wave >> 2, wc = wave & 3;       // 2 x 4 wave grid, wave tile 128x64

  int16v acc[4][2];   // 4 M-subtiles x 2 N-subtiles of 32x32
#pragma unroll
  for (int mi = 0; mi < 4; ++mi)
#pragma unroll
    for (int nj = 0; nj < 2; ++nj)
#pragma unroll
      for (int r = 0; r < 16; ++r) acc[mi][nj][r] = 0;

  // ds_read offsets (swizzled, sw = (row>>1)&3 — round-5 proven conflict-free).
  // per kstep ks2 in {0,1} within a 64B K-half: logical chunk = ks2*2 + hl.
  int aOff[2][4], bOff[2][2];
#pragma unroll
  for (int ks2 = 0; ks2 < 2; ++ks2) {
#pragma unroll
    for (int mi = 0; mi < 4; ++mi) {
      int row = wr * 128 + mi * 32 + col32;
      int sw = (row >> 1) & 3;
      aOff[ks2][mi] = row * 64 + (((ks2 * 2 + hl) ^ sw) & 3) * 16;
    }
#pragma unroll
    for (int nj = 0; nj < 2; ++nj) {
      int row = wc * 64 + nj * 32 + col32;
      int sw = (row >> 1) & 3;
      bOff[ks2][nj] = 65536 + row * 64 + (((ks2 * 2 + hl) ^ sw) & 3) * 16;
    }
  }

  // staging: half-tile = 256 rows x 64 B = 16 KiB = 2 rounds of 512 thr x 16 B.
  // linear LDS dest u*16 (row=u>>2, phys chunk=u&3) <- global logical chunk (u&3)^sw(row)
  const int u0 = tid, u1 = tid + 512;
  const int r0 = u0 >> 2, r1 = u1 >> 2;
  const int c0 = (u0 & 3) ^ ((r0 >> 1) & 3);
  const int c1 = (u1 & 3) ^ ((r1 >> 1) & 3);
  const char* gA0 = A + (size_t)(tm0 + r0) * KDIM + c0 * 16;
  const char* gA1 = A + (size_t)(tm0 + r1) * KDIM + c1 * 16;
  const char* gB0 = Bs + (size_t)(tn0 + r0) * KDIM + c0 * 16;
  const char* gB1 = Bs + (size_t)(tn0 + r1) * KDIM + c1 * 16;
  const int ldsu0 = tid * 16, ldsu1 = 8192 + tid * 16;

#define STAGE_A(BUF, KH, KOFS)                                                    \
  do {                                                                            \
    const int base_ = ((BUF) * 2 + (KH)) * 16384;                                 \
    __builtin_amdgcn_global_load_lds(                                             \
        (const __attribute__((address_space(1))) void*)(gA0 + (KOFS)),            \
        (__attribute__((address_space(3))) void*)(sm + base_ + ldsu0), 16, 0, 0); \
    __builtin_amdgcn_global_load_lds(                                             \
        (const __attribute__((address_space(1))) void*)(gA1 + (KOFS)),            \
        (__attribute__((address_space(3))) void*)(sm + base_ + ldsu1), 16, 0, 0); \
  } while (0)

#define STAGE_B(BUF, KH, KOFS)                                                    \
  do {                                                                            \
    const int base_ = 65536 + ((BUF) * 2 + (KH)) * 16384;                         \
    __builtin_amdgcn_global_load_lds(                                             \
        (const __attribute__((address_space(1))) void*)(gB0 + (KOFS)),            \
        (__attribute__((address_space(3))) void*)(sm + base_ + ldsu0), 16, 0, 0); \
    __builtin_amdgcn_global_load_lds(                                             \
        (const __attribute__((address_space(1))) void*)(gB1 + (KOFS)),            \
        (__attribute__((address_space(3))) void*)(sm + base_ + ldsu1), 16, 0, 0); \
  } while (0)

#define BAR __builtin_amdgcn_s_barrier()
#define CK4 asm volatile("s_waitcnt vmcnt(4)\n\ts_barrier" ::: "memory")
#define CK0 asm volatile("s_waitcnt vmcnt(0)\n\ts_barrier" ::: "memory")

// phase: {6 ds_read_b128 subtile + stage half-tile} -> barrier -> lgkm drain (rule 18)
// -> prio-boosted 8 x mfma_i32_32x32x32_i8 -> end barrier (CKBAR = BAR | CK4 | CK0)
#define PHASE(BUF, KS, KS2, CKBAR, ...)                                           \
  do {                                                                            \
    int4v af[4], bq[2];                                                           \
    _Pragma("unroll") for (int mi_ = 0; mi_ < 4; ++mi_)                           \
        af[mi_] = *(const int4v*)(sm + ((BUF) * 2 + (KS)) * 16384 + aOff[KS2][mi_]); \
    _Pragma("unroll") for (int nj_ = 0; nj_ < 2; ++nj_)                           \
        bq[nj_] = *(const int4v*)(sm + ((BUF) * 2 + (KS)) * 16384 + bOff[KS2][nj_]); \
    __VA_ARGS__;                                                                  \
    __builtin_amdgcn_s_barrier();                                                 \
    asm volatile("s_waitcnt lgkmcnt(0)" ::: "memory");                            \
    __builtin_amdgcn_sched_barrier(0);                                            \
    __builtin_amdgcn_s_setprio(1);                                                \
    _Pragma("unroll") for (int mi_ = 0; mi_ < 4; ++mi_)                           \
        _Pragma("unroll") for (int nj_ = 0; nj_ < 2; ++nj_)                       \
            acc[mi_][nj_] = __builtin_amdgcn_mfma_i32_32x32x32_i8(                \
                af[mi_], bq[nj_], acc[mi_][nj_], 0, 0, 0);                        \
    __builtin_amdgcn_s_setprio(0);                                                \
    CKBAR;                                                                        \
  } while (0)

// one K-tile (4 phases): compute tile TAU from BUF; stage k1(TAU+1), k0(TAU+2)
#define ITER_FULL(BUF, TAU)                                                       \
  do {                                                                            \
    PHASE(BUF, 0, 0, BAR, STAGE_A((BUF) ^ 1, 1, ((TAU) + 1) * 128 + 64));         \
    PHASE(BUF, 0, 1, BAR, STAGE_B((BUF) ^ 1, 1, ((TAU) + 1) * 128 + 64));         \
    PHASE(BUF, 1, 0, BAR, STAGE_A(BUF, 0, ((TAU) + 2) * 128));                    \
    PHASE(BUF, 1, 1, CK4, STAGE_B(BUF, 0, ((TAU) + 2) * 128));                    \
  } while (0)

  // prologue: tile0 {k0,k1} + tile1 {k0}; keep last 2 half-tiles (4 loads) in flight
  STAGE_A(0, 0, 0);
  STAGE_B(0, 0, 0);
  STAGE_A(0, 1, 64);
  STAGE_B(0, 1, 64);
  STAGE_A(1, 0, 128);
  STAGE_B(1, 0, 128);
  CK4;

  // 32 K-tiles total: steady tau = 0..29, then peeled tail
#pragma unroll 1
  for (int t = 0; t < 30; t += 2) {
    ITER_FULL(0, t);
    ITER_FULL(1, t + 1);
  }
  // tau = 30 (buf 0): stage only tile31 k1; drain at end
  PHASE(0, 0, 0, BAR, STAGE_A(1, 1, 31 * 128 + 64));
  PHASE(0, 0, 1, BAR, STAGE_B(1, 1, 31 * 128 + 64));
  PHASE(0, 1, 0, BAR, (void)0);
  PHASE(0, 1, 1, CK0, (void)0);
  // tau = 31 (buf 1): compute only
  PHASE(1, 0, 0, BAR, (void)0);
  PHASE(1, 0, 1, BAR, (void)0);
  PHASE(1, 1, 0, BAR, (void)0);
  PHASE(1, 1, 1, BAR, (void)0);

#undef ITER_FULL
#undef PHASE
#undef BAR
#undef CK4
#undef CK0
#undef STAGE_A
#undef STAGE_B

  // epilogue: C[m,n] = wscale[n]*xscale[m]*acc + wbias[n]*sumx[m]
  // 32x32 C/D layout (shape-determined, m74/m101): col = lane&31,
  // row = (reg&3) + 8*(reg>>2) + 4*(lane>>5)
  float wsv[2], wbv[2];
#pragma unroll
  for (int nj = 0; nj < 2; ++nj) {
    int n = tn0 + wc * 64 + nj * 32 + col32;
    wsv[nj] = wscale[n];
    wbv[nj] = wbias[n];
  }
#pragma unroll
  for (int mi = 0; mi < 4; ++mi) {
#pragma unroll
    for (int reg = 0; reg < 16; ++reg) {
      int m = tm0 + wr * 128 + mi * 32 + (reg & 3) + 8 * (reg >> 2) + 4 * hl;
      float xs = xscale[m];
      float sx = sumx[m];
      float* crow = C + (size_t)m * NDIM + tn0 + wc * 64 + col32;
#pragma unroll
      for (int nj = 0; nj < 2; ++nj)
        crow[nj * 32] = wsv[nj] * xs * (float)acc[mi][nj][reg] + wbv[nj] * sx;
    }
  }
}

extern "C" void kernel_launch(void* const* d_in, const int* in_sizes, int n_in,
                              void* d_out, int out_size, void* d_ws, size_t ws_size,
                              hipStream_t stream) {
  const float* x      = (const float*)d_in[0];
  const float* weight = (const float*)d_in[1];
  const float* wscale = (const float*)d_in[2];
  const float* wbias  = (const float*)d_in[3];
  float* out = (float*)d_out;

  char* xq  = (char*)d_ws;
  char* wsg = xq + (size_t)MDIM * KDIM;
  float* xscale = (float*)(wsg + (size_t)NDIM * KDIM);
  float* sumx   = xscale + MDIM;

  prep_kernel<<<MDIM + (NDIM * KDIM) / (16 * 256), 256, 0, stream>>>(
      x, weight, xq, wsg, xscale, sumx);
  gemm_bin_i8_8phase<<<(MDIM / 256) * (NDIM / 256), 512, 0, stream>>>(
      xq, wsg, wscale, wbias, xscale, sumx, out);
}

// Round 3
// 234.143 us; speedup vs baseline: 1.0109x; 1.0109x over previous
//
#include <hip/hip_runtime.h>
#include <stdint.h>

// BinaryLinearWscales: out[m,n] = wscale[n] * (x @ sign(W)^T)[m,n] + wbias[n] * rowsum(x)[m]
// M = B*S = 4096, N = DOUT = 4096, K = DIN = 4096.
// Round 8: read-ahead register pipeline on the 256x256 8-phase i8 GEMM.
//   Diagnosis (r7): phase = serial {48 ds_read (576cy) -> lgkm(0) -> 64 MFMA (585cy)}
//   = 1444 cy measured. Fix: issue phase p+1's 6 ds_reads BEFORE phase p's MFMA,
//   wait only own frags via counted lgkmcnt(6) -> LDS pipe overlaps MFMA pipe.
//   - two static frag regsets (afA/bqA, afB/bqB), alternating per phase (rule 20)
//   - intra-phase barrier dropped (end-of-phase vmcnt+barrier pairs carry all
//     hazards: reads follow the barrier that proves collective DMA completion;
//     STAGE overwrites follow the barrier after the old readers' lgkm drain)
//   - sync/tile: {BAR, BAR, vmcnt(6)+BAR, vmcnt(4)+BAR}; the new vmcnt(6) at p2
//     makes p3's cross-tile read-ahead of k0(tau+1) architecturally safe.
//   - tail: vmcnt(4)/vmcnt(0), final phase waits lgkmcnt(0), no read-ahead.
//   Conflict counter 6.29M shown to be DMA-write-side (identical across r6/r7
//   with different read patterns); expected unchanged here.

#define MDIM 4096
#define NDIM 4096
#define KDIM 4096

typedef int int4v  __attribute__((ext_vector_type(4)));
typedef int int16v __attribute__((ext_vector_type(16)));

__device__ __forceinline__ int pack4_rn(float a, float b, float c, float d, float inv) {
  int ia = __float2int_rn(a * inv) & 0xff;
  int ib = __float2int_rn(b * inv) & 0xff;
  int ic = __float2int_rn(c * inv) & 0xff;
  int id = __float2int_rn(d * inv) & 0xff;
  return ia | (ib << 8) | (ic << 16) | (id << 24);
}

__device__ __forceinline__ int sgn8(float v) {
  return (v > 0.f) ? 1 : ((v < 0.f) ? 0xff : 0);
}

// ---------------- fused prep (UNCHANGED: isolates gemm delta) ----------------
__global__ __launch_bounds__(256) void prep_kernel(
    const float* __restrict__ x, const float* __restrict__ w,
    char* __restrict__ xq, char* __restrict__ wsg,
    float* __restrict__ xscale, float* __restrict__ sumx) {
  const int b = blockIdx.x;
  const int tid = threadIdx.x;
  if (b < MDIM) {
    const int row = b;
    const float4* xr = (const float4*)(x + (size_t)row * KDIM);
    float4 v[4];
    float s = 0.f, amax = 0.f;
#pragma unroll
    for (int u = 0; u < 4; ++u) {
      v[u] = xr[u * 256 + tid];
      s += v[u].x + v[u].y + v[u].z + v[u].w;
      amax = fmaxf(amax, fmaxf(fmaxf(fabsf(v[u].x), fabsf(v[u].y)),
                               fmaxf(fabsf(v[u].z), fabsf(v[u].w))));
    }
#pragma unroll
    for (int off = 32; off > 0; off >>= 1) {
      s += __shfl_down(s, off, 64);
      amax = fmaxf(amax, __shfl_down(amax, off, 64));
    }
    __shared__ float rs[4], rm[4], bcast;
    if ((tid & 63) == 0) { rs[tid >> 6] = s; rm[tid >> 6] = amax; }
    __syncthreads();
    if (tid == 0) {
      sumx[row] = rs[0] + rs[1] + rs[2] + rs[3];
      float mt = fmaxf(fmaxf(rm[0], rm[1]), fmaxf(rm[2], rm[3]));
      xscale[row] = mt * (1.f / 127.f);
      bcast = (mt > 0.f) ? 127.f / mt : 0.f;
    }
    __syncthreads();
    const float inv = bcast;
    int* xo = (int*)(xq + (size_t)row * KDIM);
#pragma unroll
    for (int u = 0; u < 4; ++u)
      xo[u * 256 + tid] = pack4_rn(v[u].x, v[u].y, v[u].z, v[u].w, inv);
  } else {
    const size_t base = (size_t)(b - MDIM) * (256 * 4);
    const float4* wr = (const float4*)w;
    int* wo = (int*)wsg;
#pragma unroll
    for (int u = 0; u < 4; ++u) {
      size_t i = base + u * 256 + tid;
      float4 v = wr[i];
      wo[i] = sgn8(v.x) | (sgn8(v.y) << 8) | (sgn8(v.z) << 16) | (sgn8(v.w) << 24);
    }
  }
}

// ---------------- 256x256 pipelined 8-phase i8 GEMM (32x32x32 MFMA) ----------------
__global__ __launch_bounds__(512, 2) void gemm_bin_i8_pipe(
    const char* __restrict__ A, const char* __restrict__ Bs,
    const float* __restrict__ wscale, const float* __restrict__ wbias,
    const float* __restrict__ xscale, const float* __restrict__ sumx,
    float* __restrict__ C) {
  // A region: [0,64K) = (buf*2+kh)*16384 ; B region: [64K,128K)
  __shared__ __align__(16) char sm[131072];

  const int bm = blockIdx.x >> 4, bn = blockIdx.x & 15;
  const int tm0 = bm * 256, tn0 = bn * 256;
  const int tid = threadIdx.x;
  const int lane = tid & 63, wave = tid >> 6;
  const int col32 = lane & 31, hl = lane >> 5;   // 32x32 operand: row/col = lane&31, k-chunk16 = lane>>5
  const int wr = wave >> 2, wc = wave & 3;       // 2 x 4 wave grid, wave tile 128x64

  int16v acc[4][2];   // 4 M-subtiles x 2 N-subtiles of 32x32
#pragma unroll
  for (int mi = 0; mi < 4; ++mi)
#pragma unroll
    for (int nj = 0; nj < 2; ++nj)
#pragma unroll
      for (int r = 0; r < 16; ++r) acc[mi][nj][r] = 0;

  // two static fragment register sets (phase-alternating read-ahead pipeline)
  int4v afA[4], bqA[2], afB[4], bqB[2];

  // ds_read offsets (swizzle sw = (row>>1)&3; per-quarter-wave bank-uniform).
  int aOff[2][4], bOff[2][2];
#pragma unroll
  for (int ks2 = 0; ks2 < 2; ++ks2) {
#pragma unroll
    for (int mi = 0; mi < 4; ++mi) {
      int row = wr * 128 + mi * 32 + col32;
      int sw = (row >> 1) & 3;
      aOff[ks2][mi] = row * 64 + (((ks2 * 2 + hl) ^ sw) & 3) * 16;
    }
#pragma unroll
    for (int nj = 0; nj < 2; ++nj) {
      int row = wc * 64 + nj * 32 + col32;
      int sw = (row >> 1) & 3;
      bOff[ks2][nj] = 65536 + row * 64 + (((ks2 * 2 + hl) ^ sw) & 3) * 16;
    }
  }

  // staging: half-tile = 256 rows x 64 B = 16 KiB = 2 rounds of 512 thr x 16 B.
  // linear LDS dest u*16 <- global logical chunk (u&3)^sw(row)  (rule 21)
  const int u0 = tid, u1 = tid + 512;
  const int r0 = u0 >> 2, r1 = u1 >> 2;
  const int c0 = (u0 & 3) ^ ((r0 >> 1) & 3);
  const int c1 = (u1 & 3) ^ ((r1 >> 1) & 3);
  const char* gA0 = A + (size_t)(tm0 + r0) * KDIM + c0 * 16;
  const char* gA1 = A + (size_t)(tm0 + r1) * KDIM + c1 * 16;
  const char* gB0 = Bs + (size_t)(tn0 + r0) * KDIM + c0 * 16;
  const char* gB1 = Bs + (size_t)(tn0 + r1) * KDIM + c1 * 16;
  const int ldsu0 = tid * 16, ldsu1 = 8192 + tid * 16;

#define STAGE_A(BUF, KH, KOFS)                                                    \
  do {                                                                            \
    const int base_ = ((BUF) * 2 + (KH)) * 16384;                                 \
    __builtin_amdgcn_global_load_lds(                                             \
        (const __attribute__((address_space(1))) void*)(gA0 + (KOFS)),            \
        (__attribute__((address_space(3))) void*)(sm + base_ + ldsu0), 16, 0, 0); \
    __builtin_amdgcn_global_load_lds(                                             \
        (const __attribute__((address_space(1))) void*)(gA1 + (KOFS)),            \
        (__attribute__((address_space(3))) void*)(sm + base_ + ldsu1), 16, 0, 0); \
  } while (0)

#define STAGE_B(BUF, KH, KOFS)                                                    \
  do {                                                                            \
    const int base_ = 65536 + ((BUF) * 2 + (KH)) * 16384;                         \
    __builtin_amdgcn_global_load_lds(                                             \
        (const __attribute__((address_space(1))) void*)(gB0 + (KOFS)),            \
        (__attribute__((address_space(3))) void*)(sm + base_ + ldsu0), 16, 0, 0); \
    __builtin_amdgcn_global_load_lds(                                             \
        (const __attribute__((address_space(1))) void*)(gB1 + (KOFS)),            \
        (__attribute__((address_space(3))) void*)(sm + base_ + ldsu1), 16, 0, 0); \
  } while (0)

// next-phase fragment reads into regset SET from slot (BUF,KS), k-step KS2
#define DSRD(SET, BUF, KS, KS2)                                                   \
  do {                                                                            \
    _Pragma("unroll") for (int mi_ = 0; mi_ < 4; ++mi_)                           \
        af##SET[mi_] =                                                            \
            *(const int4v*)(sm + ((BUF) * 2 + (KS)) * 16384 + aOff[KS2][mi_]);    \
    _Pragma("unroll") for (int nj_ = 0; nj_ < 2; ++nj_)                           \
        bq##SET[nj_] =                                                            \
            *(const int4v*)(sm + ((BUF) * 2 + (KS)) * 16384 + bOff[KS2][nj_]);    \
  } while (0)

#define MFMA8(SET)                                                                \
  do {                                                                            \
    __builtin_amdgcn_s_setprio(1);                                                \
    _Pragma("unroll") for (int mi_ = 0; mi_ < 4; ++mi_)                           \
        _Pragma("unroll") for (int nj_ = 0; nj_ < 2; ++nj_)                       \
            acc[mi_][nj_] = __builtin_amdgcn_mfma_i32_32x32x32_i8(                \
                af##SET[mi_], bq##SET[nj_], acc[mi_][nj_], 0, 0, 0);              \
    __builtin_amdgcn_s_setprio(0);                                                \
  } while (0)

// wait own frags only: 6 newer (next phase's reads) may stay outstanding.
// sched_barrier(0) pins the MFMAs below the wait (rule 18) and the reads above.
#define WAITL6                                                                    \
  do {                                                                            \
    asm volatile("s_waitcnt lgkmcnt(6)" ::: "memory");                            \
    __builtin_amdgcn_sched_barrier(0);                                            \
  } while (0)
#define WAITL0                                                                    \
  do {                                                                            \
    asm volatile("s_waitcnt lgkmcnt(0)" ::: "memory");                            \
    __builtin_amdgcn_sched_barrier(0);                                            \
  } while (0)

#define BARO __builtin_amdgcn_s_barrier()
#define CK6  asm volatile("s_waitcnt vmcnt(6)\n\ts_barrier" ::: "memory")
#define CK4  asm volatile("s_waitcnt vmcnt(4)\n\ts_barrier" ::: "memory")
#define CK0  asm volatile("s_waitcnt vmcnt(0)\n\ts_barrier" ::: "memory")

// phase: {read next frags -> NSET ; issue STAGE} || {wait own ; MFMA CSET} ; ENDSYNC
#define PHASEP(CSET, NSET, NBUF, NKS, NKS2, STAGEOP, ENDSYNC)                     \
  do {                                                                            \
    DSRD(NSET, NBUF, NKS, NKS2);                                                  \
    STAGEOP;                                                                      \
    WAITL6;                                                                       \
    MFMA8(CSET);                                                                  \
    ENDSYNC;                                                                      \
  } while (0)

// one K-tile: compute (BUF, k0/k1, ks0/ks1); stage k1(TAU+1), k0(TAU+2).
// p2's CK6 forces k0(TAU+1) landed before p3 reads ahead into next tile.
#define TILE_MAIN(BUF, TAU)                                                       \
  do {                                                                            \
    PHASEP(A, B, BUF, 0, 1, STAGE_A((BUF) ^ 1, 1, ((TAU) + 1) * 128 + 64), BARO); \
    PHASEP(B, A, BUF, 1, 0, STAGE_B((BUF) ^ 1, 1, ((TAU) + 1) * 128 + 64), BARO); \
    PHASEP(A, B, BUF, 1, 1, STAGE_A(BUF, 0, ((TAU) + 2) * 128), CK6);             \
    PHASEP(B, A, (BUF) ^ 1, 0, 0, STAGE_B(BUF, 0, ((TAU) + 2) * 128), CK4);       \
  } while (0)

  // prologue: tile0 {k0,k1} + tile1 {k0}; CK4 leaves tile1-k0 (newest 4) in flight,
  // proves tile0 fully landed; then pre-read phase-0 fragments.
  STAGE_A(0, 0, 0);
  STAGE_B(0, 0, 0);
  STAGE_A(0, 1, 64);
  STAGE_B(0, 1, 64);
  STAGE_A(1, 0, 128);
  STAGE_B(1, 0, 128);
  CK4;
  DSRD(A, 0, 0, 0);

  // tiles 0..29
#pragma unroll 1
  for (int t = 0; t < 30; t += 2) {
    TILE_MAIN(0, t);
    TILE_MAIN(1, t + 1);
  }

  // tail tile 30 (buf 0): stage only k1(31); vmcnt(4) proves k0(31), vmcnt(0) k1(31)
  PHASEP(A, B, 0, 0, 1, STAGE_A(1, 1, 31 * 128 + 64), BARO);
  PHASEP(B, A, 0, 1, 0, STAGE_B(1, 1, 31 * 128 + 64), BARO);
  PHASEP(A, B, 0, 1, 1, (void)0, CK4);
  PHASEP(B, A, 1, 0, 0, (void)0, CK0);
  // tail tile 31 (buf 1): compute only; final phase has no read-ahead
  PHASEP(A, B, 1, 0, 1, (void)0, BARO);
  PHASEP(B, A, 1, 1, 0, (void)0, BARO);
  PHASEP(A, B, 1, 1, 1, (void)0, BARO);
  WAITL0;
  MFMA8(B);

#undef TILE_MAIN
#undef PHASEP
#undef BARO
#undef CK6
#undef CK4
#undef CK0
#undef WAITL6
#undef WAITL0
#undef MFMA8
#undef DSRD
#undef STAGE_A
#undef STAGE_B

  // epilogue: C[m,n] = wscale[n]*xscale[m]*acc + wbias[n]*sumx[m]
  // 32x32 C/D layout (shape-determined, m74/m101): col = lane&31,
  // row = (reg&3) + 8*(reg>>2) + 4*(lane>>5)
  float wsv[2], wbv[2];
#pragma unroll
  for (int nj = 0; nj < 2; ++nj) {
    int n = tn0 + wc * 64 + nj * 32 + col32;
    wsv[nj] = wscale[n];
    wbv[nj] = wbias[n];
  }
#pragma unroll
  for (int mi = 0; mi < 4; ++mi) {
#pragma unroll
    for (int reg = 0; reg < 16; ++reg) {
      int m = tm0 + wr * 128 + mi * 32 + (reg & 3) + 8 * (reg >> 2) + 4 * hl;
      float xs = xscale[m];
      float sx = sumx[m];
      float* crow = C + (size_t)m * NDIM + tn0 + wc * 64 + col32;
#pragma unroll
      for (int nj = 0; nj < 2; ++nj)
        crow[nj * 32] = wsv[nj] * xs * (float)acc[mi][nj][reg] + wbv[nj] * sx;
    }
  }
}

extern "C" void kernel_launch(void* const* d_in, const int* in_sizes, int n_in,
                              void* d_out, int out_size, void* d_ws, size_t ws_size,
                              hipStream_t stream) {
  const float* x      = (const float*)d_in[0];
  const float* weight = (const float*)d_in[1];
  const float* wscale = (const float*)d_in[2];
  const float* wbias  = (const float*)d_in[3];
  float* out = (float*)d_out;

  char* xq  = (char*)d_ws;
  char* wsg = xq + (size_t)MDIM * KDIM;
  float* xscale = (float*)(wsg + (size_t)NDIM * KDIM);
  float* sumx   = xscale + MDIM;

  prep_kernel<<<MDIM + (NDIM * KDIM) / (16 * 256), 256, 0, stream>>>(
      x, weight, xq, wsg, xscale, sumx);
  gemm_bin_i8_pipe<<<(MDIM / 256) * (NDIM / 256), 512, 0, stream>>>(
      xq, wsg, wscale, wbias, xscale, sumx, out);
}

// Round 4
// 233.021 us; speedup vs baseline: 1.0157x; 1.0048x over previous
//
#include <hip/hip_runtime.h>
#include <stdint.h>

// BinaryLinearWscales: out[m,n] = wscale[n] * (x @ sign(W)^T)[m,n] + wbias[n] * rowsum(x)[m]
// M = B*S = 4096, N = DOUT = 4096, K = DIN = 4096.
// Round 9: cut LDS-read duplication 3x -> 2x.
//   Diagnosis (r8): phase = 1350 cy; LDS pipe ~900 cy (48 ds_read 576 + DMA 320)
//   vs MFMA 585. Duplication from 2x4 wave grid (A re-read by 4 waves, B by 2).
//   Fix: 4 waves in 2x2 grid, 128x128 per-wave tile, acc[4][4] of 32x32x32 i8
//   (256 VGPR acc; 1 wave/SIMD; __launch_bounds__(256,1) -> 512-reg budget).
//   Per phase: 8 ds_read + 16 MFMA per wave -> per CU 32 reads (384cy) vs 585cy
//   MFMA: MFMA becomes the longer pipe. Read-ahead register pipeline (r8) and
//   slot/ring schedule retained; vmcnt constants doubled (4 stage instr/phase):
//   steady {BAR, BAR, vmcnt(12), vmcnt(8)}, prologue vmcnt(8), tail 8 -> 0;
//   read-ahead wait lgkmcnt(8).

#define MDIM 4096
#define NDIM 4096
#define KDIM 4096

typedef int int4v  __attribute__((ext_vector_type(4)));
typedef int int16v __attribute__((ext_vector_type(16)));

__device__ __forceinline__ int pack4_rn(float a, float b, float c, float d, float inv) {
  int ia = __float2int_rn(a * inv) & 0xff;
  int ib = __float2int_rn(b * inv) & 0xff;
  int ic = __float2int_rn(c * inv) & 0xff;
  int id = __float2int_rn(d * inv) & 0xff;
  return ia | (ib << 8) | (ic << 16) | (id << 24);
}

__device__ __forceinline__ int sgn8(float v) {
  return (v > 0.f) ? 1 : ((v < 0.f) ? 0xff : 0);
}

// ---------------- fused prep (UNCHANGED: isolates gemm delta) ----------------
__global__ __launch_bounds__(256) void prep_kernel(
    const float* __restrict__ x, const float* __restrict__ w,
    char* __restrict__ xq, char* __restrict__ wsg,
    float* __restrict__ xscale, float* __restrict__ sumx) {
  const int b = blockIdx.x;
  const int tid = threadIdx.x;
  if (b < MDIM) {
    const int row = b;
    const float4* xr = (const float4*)(x + (size_t)row * KDIM);
    float4 v[4];
    float s = 0.f, amax = 0.f;
#pragma unroll
    for (int u = 0; u < 4; ++u) {
      v[u] = xr[u * 256 + tid];
      s += v[u].x + v[u].y + v[u].z + v[u].w;
      amax = fmaxf(amax, fmaxf(fmaxf(fabsf(v[u].x), fabsf(v[u].y)),
                               fmaxf(fabsf(v[u].z), fabsf(v[u].w))));
    }
#pragma unroll
    for (int off = 32; off > 0; off >>= 1) {
      s += __shfl_down(s, off, 64);
      amax = fmaxf(amax, __shfl_down(amax, off, 64));
    }
    __shared__ float rs[4], rm[4], bcast;
    if ((tid & 63) == 0) { rs[tid >> 6] = s; rm[tid >> 6] = amax; }
    __syncthreads();
    if (tid == 0) {
      sumx[row] = rs[0] + rs[1] + rs[2] + rs[3];
      float mt = fmaxf(fmaxf(rm[0], rm[1]), fmaxf(rm[2], rm[3]));
      xscale[row] = mt * (1.f / 127.f);
      bcast = (mt > 0.f) ? 127.f / mt : 0.f;
    }
    __syncthreads();
    const float inv = bcast;
    int* xo = (int*)(xq + (size_t)row * KDIM);
#pragma unroll
    for (int u = 0; u < 4; ++u)
      xo[u * 256 + tid] = pack4_rn(v[u].x, v[u].y, v[u].z, v[u].w, inv);
  } else {
    const size_t base = (size_t)(b - MDIM) * (256 * 4);
    const float4* wr = (const float4*)w;
    int* wo = (int*)wsg;
#pragma unroll
    for (int u = 0; u < 4; ++u) {
      size_t i = base + u * 256 + tid;
      float4 v = wr[i];
      wo[i] = sgn8(v.x) | (sgn8(v.y) << 8) | (sgn8(v.z) << 16) | (sgn8(v.w) << 24);
    }
  }
}

// ---------------- 256x256, 4-wave 2x2, pipelined i8 GEMM (32x32x32) ----------------
__global__ __launch_bounds__(256, 1) void gemm_bin_i8_w4(
    const char* __restrict__ A, const char* __restrict__ Bs,
    const float* __restrict__ wscale, const float* __restrict__ wbias,
    const float* __restrict__ xscale, const float* __restrict__ sumx,
    float* __restrict__ C) {
  // A region: [0,64K) = (buf*2+kh)*16384 ; B region: [64K,128K)
  __shared__ __align__(16) char sm[131072];

  const int bm = blockIdx.x >> 4, bn = blockIdx.x & 15;
  const int tm0 = bm * 256, tn0 = bn * 256;
  const int tid = threadIdx.x;
  const int lane = tid & 63, wave = tid >> 6;
  const int col32 = lane & 31, hl = lane >> 5;  // 32x32 operand: row/col = lane&31, k16-chunk = lane>>5
  const int wr = wave >> 1, wc = wave & 1;      // 2 x 2 wave grid, wave tile 128x128

  int16v acc[4][4];   // 4 M-subtiles x 4 N-subtiles of 32x32 -> 256 VGPRs
#pragma unroll
  for (int mi = 0; mi < 4; ++mi)
#pragma unroll
    for (int nj = 0; nj < 4; ++nj)
#pragma unroll
      for (int r = 0; r < 16; ++r) acc[mi][nj][r] = 0;

  // two static fragment register sets (phase-alternating read-ahead pipeline)
  int4v afA[4], bqA[4], afB[4], bqB[4];

  // ds_read offsets (swizzle sw = (row>>1)&3).
  int aOff[2][4], bOff[2][4];
#pragma unroll
  for (int ks2 = 0; ks2 < 2; ++ks2) {
#pragma unroll
    for (int mi = 0; mi < 4; ++mi) {
      int row = wr * 128 + mi * 32 + col32;
      int sw = (row >> 1) & 3;
      aOff[ks2][mi] = row * 64 + (((ks2 * 2 + hl) ^ sw) & 3) * 16;
    }
#pragma unroll
    for (int nj = 0; nj < 4; ++nj) {
      int row = wc * 128 + nj * 32 + col32;
      int sw = (row >> 1) & 3;
      bOff[ks2][nj] = 65536 + row * 64 + (((ks2 * 2 + hl) ^ sw) & 3) * 16;
    }
  }

  // staging: half-tile = 256 rows x 64 B = 16 KiB = 4 rounds of 256 thr x 16 B.
  // unit u = tid + 256q: row = u>>2, phys chunk = u&3 = tid&3; global logical
  // chunk = (tid&3)^sw(row)  (rule 21: linear LDS dest, pre-swizzled source)
  const char* gAp[4];
  const char* gBp[4];
  int ldq[4];
#pragma unroll
  for (int q = 0; q < 4; ++q) {
    int rowq = (tid >> 2) + 64 * q;
    int cq = (tid & 3) ^ ((rowq >> 1) & 3);
    gAp[q] = A + (size_t)(tm0 + rowq) * KDIM + cq * 16;
    gBp[q] = Bs + (size_t)(tn0 + rowq) * KDIM + cq * 16;
    ldq[q] = q * 4096 + tid * 16;
  }

#define STAGE_A(BUF, KH, KOFS)                                                    \
  do {                                                                            \
    const int base_ = ((BUF) * 2 + (KH)) * 16384;                                 \
    _Pragma("unroll") for (int q_ = 0; q_ < 4; ++q_)                              \
        __builtin_amdgcn_global_load_lds(                                         \
            (const __attribute__((address_space(1))) void*)(gAp[q_] + (KOFS)),    \
            (__attribute__((address_space(3))) void*)(sm + base_ + ldq[q_]),      \
            16, 0, 0);                                                            \
  } while (0)

#define STAGE_B(BUF, KH, KOFS)                                                    \
  do {                                                                            \
    const int base_ = 65536 + ((BUF) * 2 + (KH)) * 16384;                         \
    _Pragma("unroll") for (int q_ = 0; q_ < 4; ++q_)                              \
        __builtin_amdgcn_global_load_lds(                                         \
            (const __attribute__((address_space(1))) void*)(gBp[q_] + (KOFS)),    \
            (__attribute__((address_space(3))) void*)(sm + base_ + ldq[q_]),      \
            16, 0, 0);                                                            \
  } while (0)

// next-phase fragment reads into regset SET from slot (BUF,KS), k-step KS2
#define DSRD(SET, BUF, KS, KS2)                                                   \
  do {                                                                            \
    _Pragma("unroll") for (int mi_ = 0; mi_ < 4; ++mi_)                           \
        af##SET[mi_] =                                                            \
            *(const int4v*)(sm + ((BUF) * 2 + (KS)) * 16384 + aOff[KS2][mi_]);    \
    _Pragma("unroll") for (int nj_ = 0; nj_ < 4; ++nj_)                           \
        bq##SET[nj_] =                                                            \
            *(const int4v*)(sm + ((BUF) * 2 + (KS)) * 16384 + bOff[KS2][nj_]);    \
  } while (0)

#define MFMA16(SET)                                                               \
  do {                                                                            \
    __builtin_amdgcn_s_setprio(1);                                                \
    _Pragma("unroll") for (int mi_ = 0; mi_ < 4; ++mi_)                           \
        _Pragma("unroll") for (int nj_ = 0; nj_ < 4; ++nj_)                       \
            acc[mi_][nj_] = __builtin_amdgcn_mfma_i32_32x32x32_i8(                \
                af##SET[mi_], bq##SET[nj_], acc[mi_][nj_], 0, 0, 0);              \
    __builtin_amdgcn_s_setprio(0);                                                \
  } while (0)

// wait own 8 frags only: 8 newer (next phase's reads) may stay outstanding.
#define WAITL8                                                                    \
  do {                                                                            \
    asm volatile("s_waitcnt lgkmcnt(8)" ::: "memory");                            \
    __builtin_amdgcn_sched_barrier(0);                                            \
  } while (0)
#define WAITL0                                                                    \
  do {                                                                            \
    asm volatile("s_waitcnt lgkmcnt(0)" ::: "memory");                            \
    __builtin_amdgcn_sched_barrier(0);                                            \
  } while (0)

#define BARO __builtin_amdgcn_s_barrier()
#define CK12 asm volatile("s_waitcnt vmcnt(12)\n\ts_barrier" ::: "memory")
#define CK8  asm volatile("s_waitcnt vmcnt(8)\n\ts_barrier" ::: "memory")
#define CK0  asm volatile("s_waitcnt vmcnt(0)\n\ts_barrier" ::: "memory")

// phase: {read next frags -> NSET ; issue STAGE} || {wait own ; MFMA CSET} ; ENDSYNC
#define PHASEP(CSET, NSET, NBUF, NKS, NKS2, STAGEOP, ENDSYNC)                     \
  do {                                                                            \
    DSRD(NSET, NBUF, NKS, NKS2);                                                  \
    STAGEOP;                                                                      \
    WAITL8;                                                                       \
    MFMA16(CSET);                                                                 \
    ENDSYNC;                                                                      \
  } while (0)

// one K-tile: compute (BUF, k0/k1, ks0/ks1); stage k1(TAU+1), k0(TAU+2).
// steady-state outstanding entering p0 = 8 (A,B of k0(TAU+1)); p2's CK12 drains
// them (p3 reads ahead into k0(TAU+1)); p3's CK8 drains k1(TAU+1) (read next tile).
#define TILE_MAIN(BUF, TAU)                                                       \
  do {                                                                            \
    PHASEP(A, B, BUF, 0, 1, STAGE_A((BUF) ^ 1, 1, ((TAU) + 1) * 128 + 64), BARO); \
    PHASEP(B, A, BUF, 1, 0, STAGE_B((BUF) ^ 1, 1, ((TAU) + 1) * 128 + 64), BARO); \
    PHASEP(A, B, BUF, 1, 1, STAGE_A(BUF, 0, ((TAU) + 2) * 128), CK12);            \
    PHASEP(B, A, (BUF) ^ 1, 0, 0, STAGE_B(BUF, 0, ((TAU) + 2) * 128), CK8);       \
  } while (0)

  // prologue: tile0 {k0,k1} + tile1 {k0}; CK8 keeps tile1-k0 (newest 8) in flight,
  // proves tile0 fully landed; then pre-read phase-0 fragments.
  STAGE_A(0, 0, 0);
  STAGE_B(0, 0, 0);
  STAGE_A(0, 1, 64);
  STAGE_B(0, 1, 64);
  STAGE_A(1, 0, 128);
  STAGE_B(1, 0, 128);
  CK8;
  DSRD(A, 0, 0, 0);

  // tiles 0..29
#pragma unroll 1
  for (int t = 0; t < 30; t += 2) {
    TILE_MAIN(0, t);
    TILE_MAIN(1, t + 1);
  }

  // tail tile 30 (buf 0): stage only k1(31); CK8 proves k0(31), CK0 k1(31)
  PHASEP(A, B, 0, 0, 1, STAGE_A(1, 1, 31 * 128 + 64), BARO);
  PHASEP(B, A, 0, 1, 0, STAGE_B(1, 1, 31 * 128 + 64), BARO);
  PHASEP(A, B, 0, 1, 1, (void)0, CK8);
  PHASEP(B, A, 1, 0, 0, (void)0, CK0);
  // tail tile 31 (buf 1): compute only; final phase has no read-ahead
  PHASEP(A, B, 1, 0, 1, (void)0, BARO);
  PHASEP(B, A, 1, 1, 0, (void)0, BARO);
  PHASEP(A, B, 1, 1, 1, (void)0, BARO);
  WAITL0;
  MFMA16(B);

#undef TILE_MAIN
#undef PHASEP
#undef BARO
#undef CK12
#undef CK8
#undef CK0
#undef WAITL8
#undef WAITL0
#undef MFMA16
#undef DSRD
#undef STAGE_A
#undef STAGE_B

  // epilogue: C[m,n] = wscale[n]*xscale[m]*acc + wbias[n]*sumx[m]
  // 32x32 C/D layout (shape-determined, m74/m101): col = lane&31,
  // row = (reg&3) + 8*(reg>>2) + 4*(lane>>5)
  float wsv[4], wbv[4];
#pragma unroll
  for (int nj = 0; nj < 4; ++nj) {
    int n = tn0 + wc * 128 + nj * 32 + col32;
    wsv[nj] = wscale[n];
    wbv[nj] = wbias[n];
  }
#pragma unroll
  for (int mi = 0; mi < 4; ++mi) {
#pragma unroll
    for (int reg = 0; reg < 16; ++reg) {
      int m = tm0 + wr * 128 + mi * 32 + (reg & 3) + 8 * (reg >> 2) + 4 * hl;
      float xs = xscale[m];
      float sx = sumx[m];
      float* crow = C + (size_t)m * NDIM + tn0 + wc * 128 + col32;
#pragma unroll
      for (int nj = 0; nj < 4; ++nj)
        crow[nj * 32] = wsv[nj] * xs * (float)acc[mi][nj][reg] + wbv[nj] * sx;
    }
  }
}

extern "C" void kernel_launch(void* const* d_in, const int* in_sizes, int n_in,
                              void* d_out, int out_size, void* d_ws, size_t ws_size,
                              hipStream_t stream) {
  const float* x      = (const float*)d_in[0];
  const float* weight = (const float*)d_in[1];
  const float* wscale = (const float*)d_in[2];
  const float* wbias  = (const float*)d_in[3];
  float* out = (float*)d_out;

  char* xq  = (char*)d_ws;
  char* wsg = xq + (size_t)MDIM * KDIM;
  float* xscale = (float*)(wsg + (size_t)NDIM * KDIM);
  float* sumx   = xscale + MDIM;

  prep_kernel<<<MDIM + (NDIM * KDIM) / (16 * 256), 256, 0, stream>>>(
      x, weight, xq, wsg, xscale, sumx);
  gemm_bin_i8_w4<<<(MDIM / 256) * (NDIM / 256), 256, 0, stream>>>(
      xq, wsg, wscale, wbias, xscale, sumx, out);
}